// Round 1
// baseline (11970.517 us; speedup 1.0000x reference)
//
#include <hip/hip_runtime.h>
#include <cstdint>
#include <cstddef>

typedef float f32x4 __attribute__((ext_vector_type(4)));
typedef __bf16 bf16x8 __attribute__((ext_vector_type(8)));

#define T_STEPS 256
#define BATCH   64
#define HD      1024
#define DHK     2048
#define NG      4096

__device__ __forceinline__ unsigned short f2bf(float f) {
  union { float f; unsigned u; } v; v.f = f;
  unsigned r = v.u + 0x7fffu + ((v.u >> 16) & 1u);  // RNE, inputs finite
  return (unsigned short)(r >> 16);
}

__device__ __forceinline__ float fast_sigmoid(float x) {
  return 1.0f / (1.0f + __expf(-x));
}
__device__ __forceinline__ float fast_tanh(float x) {
  float e = __expf(2.0f * x);
  return (e - 1.0f) / (e + 1.0f);
}

// Core 64x64-output GEMM tile, K reduced in steps of 32, bf16 MFMA 16x16x32.
// 256 threads = 4 waves; wave w computes all 64 rows x cols [w*16, w*16+16).
// A_SRC_EXPR / B_SRC_EXPR give per-thread 16B source pointers for staging row
// `srow` (0..63), ushort col offset `scol` (0,8,16,24), k-offset `kk`.
#define GEMM_CORE(KSTEPS, A_SRC_EXPR, B_SRC_EXPR)                              \
  __shared__ __align__(16) unsigned short Als[64 * 32];                        \
  __shared__ __align__(16) unsigned short Bls[64 * 32];                        \
  const int tid = threadIdx.x;                                                 \
  const int wv = tid >> 6;                                                     \
  const int lane = tid & 63;                                                   \
  const int l15 = lane & 15;                                                   \
  const int l16 = lane >> 4;                                                   \
  const int srow = tid >> 2;                                                   \
  const int scol = (tid & 3) << 3;                                             \
  f32x4 acc[4] = {};                                                           \
  {                                                                            \
    int kk = 0;                                                                \
    uint4 areg = *(const uint4*)(A_SRC_EXPR);                                  \
    uint4 breg = *(const uint4*)(B_SRC_EXPR);                                  \
    for (int ks = 0; ks < (KSTEPS); ++ks) {                                    \
      *(uint4*)&Als[srow * 32 + scol] = areg;                                  \
      *(uint4*)&Bls[srow * 32 + scol] = breg;                                  \
      __syncthreads();                                                         \
      if (ks + 1 < (KSTEPS)) {                                                 \
        kk = (ks + 1) * 32;                                                    \
        areg = *(const uint4*)(A_SRC_EXPR);                                    \
        breg = *(const uint4*)(B_SRC_EXPR);                                    \
      }                                                                        \
      bf16x8 bfrag = *(const bf16x8*)&Bls[(wv * 16 + l15) * 32 + l16 * 8];     \
      _Pragma("unroll")                                                        \
      for (int mt = 0; mt < 4; ++mt) {                                         \
        bf16x8 afrag = *(const bf16x8*)&Als[(mt * 16 + l15) * 32 + l16 * 8];   \
        acc[mt] =                                                              \
            __builtin_amdgcn_mfma_f32_16x16x32_bf16(afrag, bfrag, acc[mt],     \
                                                    0, 0, 0);                  \
      }                                                                        \
      __syncthreads();                                                         \
    }                                                                          \
  }

// ---- per-step kernel 1: gate pre-activations + activations -----------------
// preact[b, n] = sum_k comb[b,k] * W[n,k] + bias[n], comb = [x_t | h]
// G[gate*64 + b][h] = act(preact), act = tanh for gate 2 else sigmoid
__global__ __launch_bounds__(256) void k1_gates(
    const unsigned short* __restrict__ Xbf, const unsigned short* __restrict__ hbf,
    const unsigned short* __restrict__ Wbf, const float* __restrict__ bias_cat,
    unsigned short* __restrict__ Gbf, int t) {
  const int n0 = blockIdx.x * 64;  // 64 blocks over N=4096
  GEMM_CORE(64,
    (kk < 1024 ? Xbf + ((size_t)(t * BATCH + srow)) * HD + kk + scol
               : hbf + (size_t)srow * HD + (kk - 1024) + scol),
    (Wbf + (size_t)(n0 + srow) * DHK + kk + scol))
  const int gate = n0 >> 10;               // uniform per block (64 | 1024)
  const int ncol = n0 + wv * 16 + l15;
  const int hcol = ncol & (HD - 1);
  const float bias = bias_cat[ncol];
#pragma unroll
  for (int mt = 0; mt < 4; ++mt) {
#pragma unroll
    for (int r = 0; r < 4; ++r) {
      const int b = mt * 16 + l16 * 4 + r;
      float v = acc[mt][r] + bias;
      v = (gate == 2) ? fast_tanh(v) : fast_sigmoid(v);
      Gbf[(size_t)(gate * BATCH + b) * HD + hcol] = f2bf(v);
    }
  }
}

// ---- per-step kernel 2: qc layer (depth 0) ---------------------------------
// Gout[row, n] = tanh(sum_k Gin[row,k]*qcw[n,k] + qcb[n]), rows = [256]
__global__ __launch_bounds__(256) void k2_qc(
    const unsigned short* __restrict__ Gin, const unsigned short* __restrict__ qcw,
    const float* __restrict__ qcb, unsigned short* __restrict__ Gout) {
  const int rt = blockIdx.x >> 4;          // 4 row-tiles of 64
  const int n0 = (blockIdx.x & 15) * 64;   // 16 col-tiles of 64
  GEMM_CORE(32,
    (Gin + (size_t)(rt * 64 + srow) * HD + kk + scol),
    (qcw + (size_t)(n0 + srow) * HD + kk + scol))
  const int ncol = n0 + wv * 16 + l15;
  const float qb = qcb[ncol];
#pragma unroll
  for (int mt = 0; mt < 4; ++mt) {
#pragma unroll
    for (int r = 0; r < 4; ++r) {
      const int row = rt * 64 + mt * 16 + l16 * 4 + r;
      Gout[(size_t)row * HD + ncol] = f2bf(fast_tanh(acc[mt][r] + qb));
    }
  }
}

// ---- per-step kernel 3: qc layer (depth 1) fused with cell update ----------
// Tile rows gathered as (gate g, batch bt*16+bb): tile row = g*16+bb, so
// m-subtile index == gate, and f/i/g/o for one (b,h) share a lane+reg.
__global__ __launch_bounds__(256) void k3_qc_update(
    const unsigned short* __restrict__ Gin, const unsigned short* __restrict__ qcw,
    const float* __restrict__ qcb, float* __restrict__ c_state,
    unsigned short* __restrict__ hbf, float* __restrict__ out, int t) {
  const int bt = blockIdx.x >> 4;          // 4 batch-tiles of 16
  const int n0 = (blockIdx.x & 15) * 64;   // 16 col-tiles of 64
  GEMM_CORE(32,
    (Gin + (size_t)((srow >> 4) * BATCH + bt * 16 + (srow & 15)) * HD + kk + scol),
    (qcw + (size_t)(n0 + srow) * HD + kk + scol))
  const int hcol = n0 + wv * 16 + l15;
  const float qb = qcb[hcol];
#pragma unroll
  for (int r = 0; r < 4; ++r) {
    const int b = bt * 16 + l16 * 4 + r;
    const float fg = fast_tanh(acc[0][r] + qb);
    const float ig = fast_tanh(acc[1][r] + qb);
    const float gg = fast_tanh(acc[2][r] + qb);
    const float og = fast_tanh(acc[3][r] + qb);
    const int ci = b * HD + hcol;
    const float c_new = fg * c_state[ci] + ig * gg;
    const float h_new = og * fast_tanh(c_new);
    c_state[ci] = c_new;
    out[(size_t)t * (BATCH * HD) + ci] = h_new;
    hbf[ci] = f2bf(h_new);
    if (t == T_STEPS - 1) {
      out[(size_t)T_STEPS * (BATCH * HD) + ci] = h_new;            // hx
      out[(size_t)T_STEPS * (BATCH * HD) + BATCH * HD + ci] = c_new; // cx
    }
  }
}

// ---- prep kernels ----------------------------------------------------------
__global__ void xconv_kernel(const float* __restrict__ x,
                             unsigned short* __restrict__ xbf, int n4) {
  int idx = blockIdx.x * blockDim.x + threadIdx.x;
  int stride = gridDim.x * blockDim.x;
  for (int i = idx; i < n4; i += stride) {
    float4 v = ((const float4*)x)[i];
    ushort4 o;
    o.x = f2bf(v.x); o.y = f2bf(v.y); o.z = f2bf(v.z); o.w = f2bf(v.w);
    ((ushort4*)xbf)[i] = o;
  }
}

__global__ void wconv_kernel(const float* __restrict__ Wf, const float* __restrict__ Wi,
                             const float* __restrict__ Wu, const float* __restrict__ Wo,
                             const float* __restrict__ bfv, const float* __restrict__ biv,
                             const float* __restrict__ buv, const float* __restrict__ bov,
                             unsigned short* __restrict__ Wbf, float* __restrict__ bias_cat) {
  const int n = blockIdx.x;                 // 0..4095
  const int gate = n >> 10, r = n & 1023;
  const float* W = gate == 0 ? Wf : gate == 1 ? Wi : gate == 2 ? Wu : Wo;
  const float* src = W + (size_t)r * DHK;
  unsigned short* dst = Wbf + (size_t)n * DHK;
  for (int k = threadIdx.x; k < DHK; k += 256) dst[k] = f2bf(src[k]);
  if (threadIdx.x == 0) {
    const float* bsrc = gate == 0 ? bfv : gate == 1 ? biv : gate == 2 ? buv : bov;
    bias_cat[n] = bsrc[r];
  }
}

__global__ void qcw_kernel(const float* __restrict__ qcv, const float* __restrict__ qcg,
                           unsigned short* __restrict__ qcw) {
  const int row = blockIdx.x * 4 + (threadIdx.x >> 6);  // 0..2047 (= d*1024 + o)
  const int lane = threadIdx.x & 63;
  const float* v = qcv + (size_t)row * HD;
  float ss = 0.0f;
#pragma unroll
  for (int j = 0; j < 16; ++j) { float a = v[j * 64 + lane]; ss += a * a; }
#pragma unroll
  for (int off = 32; off > 0; off >>= 1) ss += __shfl_xor(ss, off);
  const float scale = qcg[row] / sqrtf(ss);
#pragma unroll
  for (int j = 0; j < 16; ++j)
    qcw[(size_t)row * HD + j * 64 + lane] = f2bf(v[j * 64 + lane] * scale);
}

__global__ void init_state_kernel(unsigned short* __restrict__ hbf,
                                  float* __restrict__ c_state) {
  int i = blockIdx.x * blockDim.x + threadIdx.x;  // 65536 launched
  hbf[i] = 0;
  c_state[i] = 0.0f;
}

// ---- launcher --------------------------------------------------------------
extern "C" void kernel_launch(void* const* d_in, const int* in_sizes, int n_in,
                              void* d_out, int out_size, void* d_ws, size_t ws_size,
                              hipStream_t stream) {
  const float* x   = (const float*)d_in[0];
  const float* Wf  = (const float*)d_in[1];
  const float* bfv = (const float*)d_in[2];
  const float* Wi  = (const float*)d_in[3];
  const float* biv = (const float*)d_in[4];
  const float* Wu  = (const float*)d_in[5];
  const float* buv = (const float*)d_in[6];
  const float* Wo  = (const float*)d_in[7];
  const float* bov = (const float*)d_in[8];
  const float* qcv = (const float*)d_in[9];
  const float* qcg = (const float*)d_in[10];
  const float* qcb = (const float*)d_in[11];
  float* out = (float*)d_out;

  char* p = (char*)d_ws;
  auto alloc = [&](size_t bytes) {
    char* r = p; p += (bytes + 255) & ~(size_t)255; return r;
  };
  unsigned short* Xbf  = (unsigned short*)alloc((size_t)T_STEPS * BATCH * HD * 2); // 33.6 MB
  unsigned short* Wbf  = (unsigned short*)alloc((size_t)NG * DHK * 2);             // 16.8 MB
  unsigned short* qcw  = (unsigned short*)alloc((size_t)2 * HD * HD * 2);          //  4.2 MB
  float* bias_cat      = (float*)alloc((size_t)NG * 4);
  unsigned short* Gbf  = (unsigned short*)alloc((size_t)4 * BATCH * HD * 2);
  unsigned short* G2bf = (unsigned short*)alloc((size_t)4 * BATCH * HD * 2);
  unsigned short* hbf  = (unsigned short*)alloc((size_t)BATCH * HD * 2);
  float* c_state       = (float*)alloc((size_t)BATCH * HD * 4);

  init_state_kernel<<<256, 256, 0, stream>>>(hbf, c_state);
  xconv_kernel<<<2048, 256, 0, stream>>>(x, Xbf, T_STEPS * BATCH * HD / 4);
  wconv_kernel<<<NG, 256, 0, stream>>>(Wf, Wi, Wu, Wo, bfv, biv, buv, bov,
                                       Wbf, bias_cat);
  qcw_kernel<<<512, 256, 0, stream>>>(qcv, qcg, qcw);

  for (int t = 0; t < T_STEPS; ++t) {
    k1_gates<<<64, 256, 0, stream>>>(Xbf, hbf, Wbf, bias_cat, Gbf, t);
    k2_qc<<<64, 256, 0, stream>>>(Gbf, qcw, qcb, G2bf);
    k3_qc_update<<<64, 256, 0, stream>>>(G2bf, qcw + (size_t)HD * HD, qcb + HD,
                                         c_state, hbf, out, t);
  }
}